// Round 3
// baseline (1021.716 us; speedup 1.0000x reference)
//
#include <hip/hip_runtime.h>

// WindowAttention (Swin-style, softmax over HEADS axis per reference).
// B=4096 blocks, 512 threads (8 waves = 1 head each). bf16 MFMA 16x16x32.
// LDS: q[8][64][40]bf16 (40,960B) + k same + attn[8][64][72]bf16 (73,728B)
//      = 155,648B dynamic; v[8][32][72] overlays q after the QK barrier.
// Occupancy: 1 block/CU (LDS-bound), 16 blocks sequential per CU.

#define TPB 512
#define SCALE_Q 0.17677669529663687f

typedef __bf16 bf16x8 __attribute__((ext_vector_type(8)));
typedef float floatx4 __attribute__((ext_vector_type(4)));
typedef unsigned short ushortx8 __attribute__((ext_vector_type(8)));
typedef unsigned short ushortx4 __attribute__((ext_vector_type(4)));

__device__ __forceinline__ unsigned short f2bf(float f) {
  unsigned int u = __float_as_uint(f);
  u = (u + 0x7fffu + ((u >> 16) & 1u)) >> 16;   // RNE; inputs finite
  return (unsigned short)u;
}
__device__ __forceinline__ float bf2f(unsigned short h) {
  return __uint_as_float(((unsigned int)h) << 16);
}

extern "C" __global__ void __launch_bounds__(TPB)
wa_kernel(const float* __restrict__ qkv, const float* __restrict__ maskp,
          const float* __restrict__ table, const int* __restrict__ ridx,
          float* __restrict__ out)
{
  extern __shared__ unsigned short sm[];
  unsigned short* qsm  = sm;           // 20480 ushorts: q[h][t<64][c pad 40]
  unsigned short* ksm  = sm + 20480;   // 20480 ushorts: k[h][s<64][c pad 40]
  unsigned short* atn  = sm + 40960;   // 36864 ushorts: attn[h][t<64][s pad 72]
  unsigned short* vsm  = sm;           // overlays q: v[h][c<32][s pad 72]

  const int tid  = threadIdx.x;
  const int b    = blockIdx.x;
  const int w    = b & 63;             // window = b % 64
  const int lane = tid & 63;
  const int wv   = tid >> 6;           // wave id == head id
  const int lm   = lane & 15;
  const int lk   = lane >> 4;
  const float* qkvb = qkv + (size_t)b * 37632;   // 768*49

  // ---- phase 1a: q,k global -> regs (consumed first: issue first) ----
  // 1664 tasks = 2 tensors * 8 heads * 8 cgroups * 13 tgroups
  float qkr[4][4][4];
  #pragma unroll
  for (int it = 0; it < 4; ++it) {
    int task = tid + it * TPB;
    if (task < 1664) {
      int tensor = task >= 832 ? 1 : 0;
      int tq = task - tensor * 832;
      int h  = tq / 104;
      int r  = tq - h * 104;
      int cg = r / 13;
      int tb = r - cg * 13;
      const float* g = qkvb + (h * 96 + tensor * 32 + cg * 4) * 49 + tb * 4;
      int maxo = 48 - tb * 4;           // clamp keeps reads in-bounds
      #pragma unroll
      for (int cc = 0; cc < 4; ++cc)
        #pragma unroll
        for (int t2 = 0; t2 < 4; ++t2)
          qkr[it][cc][t2] = g[cc * 49 + (t2 <= maxo ? t2 : maxo)];
    }
  }

  // ---- phase 1b: v global -> regs (consumed after softmax) ----
  float vr[8][4];
  #pragma unroll
  for (int it = 0; it < 8; ++it) {
    int task = tid + it * TPB;          // 8*32*16 = 4096 tasks
    int h  = task >> 9;
    int r  = task & 511;
    int c  = r >> 4;
    int sg = r & 15;
    if (sg < 13) {
      const float* vg = qkvb + (h * 96 + 64 + c) * 49 + sg * 4;
      int maxo = 48 - sg * 4;
      #pragma unroll
      for (int ss = 0; ss < 4; ++ss) {
        float val = vg[ss <= maxo ? ss : maxo];
        vr[it][ss] = (ss <= maxo) ? val : 0.f;   // s in [49,64) must be ZERO
      }
    } else {
      #pragma unroll
      for (int ss = 0; ss < 4; ++ss) vr[it][ss] = 0.f;
    }
  }

  // ---- phase 1c: q,k regs -> LDS bf16, transposed to [h][t][c] ----
  #pragma unroll
  for (int it = 0; it < 4; ++it) {
    int task = tid + it * TPB;
    if (task < 1664) {
      int tensor = task >= 832 ? 1 : 0;
      int tq = task - tensor * 832;
      int h  = tq / 104;
      int r  = tq - h * 104;
      int cg = r / 13;
      int tb = r - cg * 13;
      float sc = tensor ? 1.f : SCALE_Q;   // fold scale into q
      unsigned short* dst = (tensor ? ksm : qsm) + h * 2560 + (tb * 4) * 40 + cg * 4;
      #pragma unroll
      for (int t2 = 0; t2 < 4; ++t2) {
        ushortx4 wv4;
        #pragma unroll
        for (int cc = 0; cc < 4; ++cc) wv4[cc] = f2bf(qkr[it][cc][t2] * sc);
        *(ushortx4*)(dst + t2 * 40) = wv4;
      }
    }
  }
  __syncthreads();

  // ---- phase 2: QK^T (one head per wave), logits -> attn LDS (bf16) ----
  {
    const unsigned short* qh = qsm + wv * 2560;
    const unsigned short* kh = ksm + wv * 2560;
    unsigned short* ah = atn + wv * 4608;
    #pragma unroll
    for (int tt = 0; tt < 4; ++tt) {
      bf16x8 afr = __builtin_bit_cast(bf16x8,
          *(const ushortx8*)(qh + (tt * 16 + lm) * 40 + lk * 8));
      #pragma unroll
      for (int ts = 0; ts < 4; ++ts) {
        bf16x8 bfr = __builtin_bit_cast(bf16x8,
            *(const ushortx8*)(kh + (ts * 16 + lm) * 40 + lk * 8));
        floatx4 acc = {0.f, 0.f, 0.f, 0.f};
        acc = __builtin_amdgcn_mfma_f32_16x16x32_bf16(afr, bfr, acc, 0, 0, 0);
        int s = ts * 16 + lm;           // D col = lane&15
        if (s < 49) {
          #pragma unroll
          for (int j = 0; j < 4; ++j) {
            int t = tt * 16 + lk * 4 + j;   // D row = (lane>>4)*4+j
            ah[t * 72 + s] = f2bf(acc[j]);
          }
        }
      }
    }
  }
  __syncthreads();

  // ---- phase 3a: softmax over heads at each (t<49, s<64) ----
  #pragma unroll
  for (int it = 0; it < 7; ++it) {
    int task = tid + it * TPB;          // 49*64 = 3136 tasks
    if (task < 3136) {
      int t = task >> 6, s = task & 63;
      if (s >= 49) {                    // zero K-dim padding of PV
        #pragma unroll
        for (int h = 0; h < 8; ++h) atn[h * 4608 + t * 72 + s] = 0;
      } else {
        float mk = maskp[w * 2401 + t * 49 + s];
        int idx = ridx[t * 49 + s];
        const float4* tb4 = (const float4*)(table + idx * 8);
        float4 b0 = tb4[0], b1 = tb4[1];
        float lg[8];
        #pragma unroll
        for (int h = 0; h < 8; ++h) lg[h] = bf2f(atn[h * 4608 + t * 72 + s]) + mk;
        lg[0] += b0.x; lg[1] += b0.y; lg[2] += b0.z; lg[3] += b0.w;
        lg[4] += b1.x; lg[5] += b1.y; lg[6] += b1.z; lg[7] += b1.w;
        float m = lg[0];
        #pragma unroll
        for (int h = 1; h < 8; ++h) m = fmaxf(m, lg[h]);
        float e[8]; float ssum = 0.f;
        #pragma unroll
        for (int h = 0; h < 8; ++h) { e[h] = __expf(lg[h] - m); ssum += e[h]; }
        float inv = 1.f / ssum;
        #pragma unroll
        for (int h = 0; h < 8; ++h) atn[h * 4608 + t * 72 + s] = f2bf(e[h] * inv);
      }
    }
  }

  // ---- phase 3b: v regs -> LDS [h][c][s] (overlays q; q reads all done) ----
  #pragma unroll
  for (int it = 0; it < 8; ++it) {
    int task = tid + it * TPB;
    int h  = task >> 9;
    int r  = task & 511;
    int c  = r >> 4;
    int sg = r & 15;
    ushortx4 wv4;
    #pragma unroll
    for (int ss = 0; ss < 4; ++ss) wv4[ss] = f2bf(vr[it][ss]);
    *(ushortx4*)(vsm + h * 2304 + c * 72 + sg * 4) = wv4;
  }
  __syncthreads();

  // ---- phase 4: PV (one head per wave), fp32 stores ----
  {
    const unsigned short* ah = atn + wv * 4608;
    const unsigned short* vh = vsm + wv * 2304;
    float* outh = out + (size_t)b * 12544 + wv * 32 * 49;
    #pragma unroll
    for (int tt = 0; tt < 4; ++tt) {
      #pragma unroll
      for (int tc = 0; tc < 2; ++tc) {
        floatx4 acc = {0.f, 0.f, 0.f, 0.f};
        #pragma unroll
        for (int kk = 0; kk < 2; ++kk) {
          bf16x8 afr = __builtin_bit_cast(bf16x8,
              *(const ushortx8*)(ah + (tt * 16 + lm) * 72 + kk * 32 + lk * 8));
          bf16x8 bfr = __builtin_bit_cast(bf16x8,
              *(const ushortx8*)(vh + (tc * 16 + lm) * 72 + kk * 32 + lk * 8));
          acc = __builtin_amdgcn_mfma_f32_16x16x32_bf16(afr, bfr, acc, 0, 0, 0);
        }
        #pragma unroll
        for (int j = 0; j < 4; ++j) {
          int t = tt * 16 + lk * 4 + j;
          if (t < 49) outh[(tc * 16 + lm) * 49 + t] = acc[j];
        }
      }
    }
  }
}

extern "C" void kernel_launch(void* const* d_in, const int* in_sizes, int n_in,
                              void* d_out, int out_size, void* d_ws, size_t ws_size,
                              hipStream_t stream) {
  const float* qkv   = (const float*)d_in[0];
  const float* maskp = (const float*)d_in[1];
  const float* table = (const float*)d_in[2];
  const int*   ridx  = (const int*)d_in[3];
  float* out = (float*)d_out;

  (void)in_sizes; (void)n_in; (void)out_size; (void)d_ws; (void)ws_size;

  const int smem_bytes = 155648;  // 152 KB of the 160 KB/CU pool
  hipFuncSetAttribute((const void*)wa_kernel,
                      hipFuncAttributeMaxDynamicSharedMemorySize, smem_bytes);
  wa_kernel<<<4096, TPB, smem_bytes, stream>>>(qkv, maskp, table, ridx, out);
}